// Round 4
// baseline (275.592 us; speedup 1.0000x reference)
//
#include <hip/hip_runtime.h>
#include <math.h>

#define HH 1536
#define WW 1536
#define HWSZ (HH*WW)
#define NT 384   // one row per block: 384 threads x 4 px = 1536. Known-good codegen.
#define NBLK HH

// Lessons (rounds 1-3):
//  - 256-thread blocks trigger an 8-waves/EU (64 VGPR) allocator target and
//    ~23 floats/thread of scratch spill; amdgpu_waves_per_eu(4,4) does NOT fix it.
//    The 384-thread one-row-per-block framing reliably gets ~112 VGPR, no spill.
//  - Replacing the x-halo loads with __shfl chains made the kernel SLOWER
//    (114.6 -> 144 us): dependent ds_bpermute + 2-lane fixup loads serialize the
//    per-channel critical path, while redundant all-lane halo loads are
//    independent VMEM that pipelines (latency-bound regime). Keep the loads.

__device__ __forceinline__ float4 LD4(const float* __restrict__ p, int row, int t) {
    return reinterpret_cast<const float4*>(p + row)[t];
}

__global__ __launch_bounds__(NT) void step_kernel(
    const float* __restrict__ phi,
    const float* __restrict__ sensory,
    const float* __restrict__ gamma,
    const float* __restrict__ alpha,
    const float* __restrict__ mixw,
    float* __restrict__ out,
    float* __restrict__ sums)     // ws: sums[0..9], done-counter at sums[10]
{
    // mix rows padded to 12 floats -> 48B rows, float4/float2 reads stay aligned
    __shared__ float s_mix[10][12];
    __shared__ float s_red[6][10];

    const int tid = threadIdx.x;
    if (tid < 100) s_mix[tid / 10][tid % 10] = mixw[tid];
    // no barrier: s_mix is first read after the mid-kernel __syncthreads

    // XCD-banded swizzle: blocks dispatch round-robin over 8 XCDs; give each
    // XCD a contiguous 192-row band so stencil row-reuse hits its own L2.
    const int blk = blockIdx.x;
    const int y = (blk & 7) * 192 + (blk >> 3);

    const int x0 = tid * 4;

    const int ym1 = (y == 0)      ? HH - 1     : y - 1;
    const int yp1 = (y == HH - 1) ? 0          : y + 1;
    const int ym2 = (y < 2)       ? y + HH - 2 : y - 2;
    const int yp2 = (y >= HH - 2) ? y - HH + 2 : y + 2;

    const int r0  = y   * WW;
    const int rm1 = ym1 * WW;
    const int rp1 = yp1 * WW;
    const int rm2 = ym2 * WW;
    const int rp2 = yp2 * WW;

    // x halo indices (x0 is a multiple of 4, so x0==0 is the only left wrap)
    const int xl1 = (x0 == 0)        ? WW - 1 : x0 - 1;
    const int xl2 = (x0 == 0)        ? WW - 2 : x0 - 2;
    const int xr1 = (x0 + 4 == WW)   ? 0      : x0 + 4;
    const int xr2 = (x0 + 4 == WW)   ? 1      : x0 + 5;

    // gamma/alpha: wave-uniform indices on const restrict ptr -> scalar loads
    const float g0 = gamma[0], g1 = gamma[1], g2 = gamma[2], g3 = gamma[3], g4 = gamma[4];
    const float g5 = gamma[5], g6 = gamma[6], g7 = gamma[7], g8 = gamma[8], g9 = gamma[9];
    const float a0 = alpha[0];

    float pv[10][4];   // phi values (kept for coupling)
    float dv[10][4];   // per-channel dphi (nonlinear + lap/bilap part)

    #pragma unroll
    for (int c = 0; c < 10; ++c) {
        const float* pc = phi + (size_t)c * HWSZ;
        const float4 cm = LD4(pc, r0,  tid);
        const float4 nn = LD4(pc, rm1, tid);
        const float4 ss = LD4(pc, rp1, tid);
        const float wl1 = pc[r0 + xl1];
        const float wr1 = pc[r0 + xr1];

        float lap[4];
        lap[0] = nn.x + ss.x + wl1  + cm.y - 4.0f * cm.x;
        lap[1] = nn.y + ss.y + cm.x + cm.z - 4.0f * cm.y;
        lap[2] = nn.z + ss.z + cm.y + cm.w - 4.0f * cm.z;
        lap[3] = nn.w + ss.w + cm.z + wr1  - 4.0f * cm.w;

        float bl[4] = {0.f, 0.f, 0.f, 0.f};
        if (c == 0 || c == 3 || c == 4 || c == 9) {
            // direct 13-pt bilaplacian: 20c -8(N+S+W+E) +2(diag) + (NN+SS+WW+EE)
            const float4 t2n = LD4(pc, rm2, tid);
            const float4 t2s = LD4(pc, rp2, tid);
            const float wl2 = pc[r0  + xl2];
            const float wr2 = pc[r0  + xr2];
            const float nwl = pc[rm1 + xl1];
            const float ner = pc[rm1 + xr1];
            const float swl = pc[rp1 + xl1];
            const float ser = pc[rp1 + xr1];
            bl[0] = 20.0f*cm.x - 8.0f*(nn.x + ss.x + wl1  + cm.y)
                  + 2.0f*(nwl  + nn.y + swl  + ss.y) + (t2n.x + t2s.x + wl2  + cm.z);
            bl[1] = 20.0f*cm.y - 8.0f*(nn.y + ss.y + cm.x + cm.z)
                  + 2.0f*(nn.x + nn.z + ss.x + ss.z) + (t2n.y + t2s.y + wl1  + cm.w);
            bl[2] = 20.0f*cm.z - 8.0f*(nn.z + ss.z + cm.y + cm.w)
                  + 2.0f*(nn.y + nn.w + ss.y + ss.w) + (t2n.z + t2s.z + cm.x + wr1);
            bl[3] = 20.0f*cm.w - 8.0f*(nn.w + ss.w + cm.z + wr1)
                  + 2.0f*(nn.z + ner  + ss.z + ser ) + (t2n.w + t2s.w + cm.y + wr2);
        }

        pv[c][0] = cm.x; pv[c][1] = cm.y; pv[c][2] = cm.z; pv[c][3] = cm.w;

        #pragma unroll
        for (int k = 0; k < 4; ++k) {
            const float pp = pv[c][k];
            const float lv = lap[k];
            const float bv = bl[k];
            float dd;
            switch (c) {
            case 0: dd = -g0*lv - a0*pp*pp*pp + 0.12f*bv; break;
            case 1: dd = -g1*lv + 0.15f*__sinf(pp) + 0.08f*pp*pp*pp; break;
            case 2: dd = -g2*lv + 0.2f*pp*(1.0f - pp*pp); break;
            case 3: { const float p2 = pp*pp;
                      dd = -g3*lv - 0.03f*p2*p2*pp + 0.08f*bv; } break;
            case 4: dd = -g4*lv + 0.12f*pp*__logf(fabsf(pp) + 1e-6f) + 0.02f*bv; break;
            case 5: { const float p2 = pp*pp;
                      dd = -g5*lv + 0.08f*p2*pp - 0.02f*p2*p2*pp; } break;
            case 6: { const float p2 = pp*pp;
                      dd = -g6*lv + 0.06f*p2*p2 - 0.04f*pp; } break;
            case 7: { const float pc7 = fminf(fmaxf(pp, -2.0f), 2.0f);
                      const float ex  = __expf(pc7);
                      const float exm = __expf(-pc7);
                      dd = -g7*lv + 0.04f*(ex - exm); } break;   // 0.08*sinh = 0.04*(e^x - e^-x)
            case 8: dd = -g8*lv + 0.05f*pp*pp - 0.08f*pp; break;
            default: { const float p3 = pp*pp*pp;
                       dd = -g9*lv + 0.02f*p3*p3 - 0.04f*p3 + 0.01f*bv; } break;
            }
            dv[c][k] = dd;
        }
    }

    float fmv[4], smv[4], sdk[4];
    {
        const float4 sd4 = LD4(sensory, r0, tid);
        sdk[0] = sd4.x; sdk[1] = sd4.y; sdk[2] = sd4.z; sdk[3] = sd4.w;
        #pragma unroll
        for (int k = 0; k < 4; ++k) {
            fmv[k] = (pv[0][k] + pv[1][k] + pv[2][k] + pv[3][k] + pv[4][k]) * 0.2f;
            smv[k] = (pv[5][k] + pv[6][k] + pv[7][k] + pv[8][k] + pv[9][k]) * 0.2f;
        }
    }

    __syncthreads();   // s_mix visible before coupling reads

    const int lane = tid & 63;
    const int wave = tid >> 6;

    #pragma unroll
    for (int o = 0; o < 10; ++o) {
        const float4 m0 = *reinterpret_cast<const float4*>(&s_mix[o][0]);
        const float4 m1 = *reinterpret_cast<const float4*>(&s_mix[o][4]);
        const float2 m2 = *reinterpret_cast<const float2*>(&s_mix[o][8]);
        float pn[4];
        #pragma unroll
        for (int k = 0; k < 4; ++k) {
            float cp;
            cp = m0.x * pv[0][k];
            cp = fmaf(m0.y, pv[1][k], cp);
            cp = fmaf(m0.z, pv[2][k], cp);
            cp = fmaf(m0.w, pv[3][k], cp);
            cp = fmaf(m1.x, pv[4][k], cp);
            cp = fmaf(m1.y, pv[5][k], cp);
            cp = fmaf(m1.z, pv[6][k], cp);
            cp = fmaf(m1.w, pv[7][k], cp);
            cp = fmaf(m2.x, pv[8][k], cp);
            cp = fmaf(m2.y, pv[9][k], cp);
            float dd = dv[o][k];
            if (o < 5) {
                dd += 0.06f * cp + 0.02f * smv[k];          // EPS_FAST, S2F
                if (o == 0) dd += 0.2f  * sdk[k];
                if (o == 4) dd += 0.08f * fabsf(sdk[k]);
                pn[k] = pv[o][k] + 0.02f * dd;              // DT * FAST_DT
            } else {
                dd += 0.02f * cp + 0.04f * fmv[k];          // EPS_SLOW, F2S
                if (o == 9) dd += 0.05f * sdk[k];
                pn[k] = pv[o][k] + 0.004f * dd;             // DT * SLOW_DT
            }
            pn[k] = fminf(fmaxf(pn[k], -4.0f), 4.0f);
        }
        float4 o4; o4.x = pn[0]; o4.y = pn[1]; o4.z = pn[2]; o4.w = pn[3];
        reinterpret_cast<float4*>(out + (size_t)o * HWSZ + r0)[tid] = o4;

        float s = pn[0] + pn[1] + pn[2] + pn[3];
        #pragma unroll
        for (int off = 32; off > 0; off >>= 1) s += __shfl_down(s, off, 64);
        if (lane == 0) s_red[wave][o] = s;
    }

    __syncthreads();
    if (tid < 10) {
        float v = 0.0f;
        #pragma unroll
        for (int w = 0; w < 6; ++w) v += s_red[w][tid];
        atomicAdd(&sums[tid], v);
    }

    // Fused finalize: tid 0 is in the same wave as tids 1-9; threadfence orders
    // their sums-atomics before the counter bump. Last-done block reads totals
    // coherently and writes the 12 scalar outputs. Saves one dispatch.
    if (tid == 0) {
        __threadfence();
        unsigned int* cnt = reinterpret_cast<unsigned int*>(sums + 10);
        const unsigned int old = atomicAdd(cnt, 1u);
        if (old == (unsigned int)(NBLK - 1)) {
            const float inv = 1.0f / (float)HWSZ;
            const size_t base = (size_t)10 * HWSZ;
            float sv[10];
            #pragma unroll
            for (int i = 0; i < 10; ++i) sv[i] = atomicAdd(&sums[i], 0.0f);  // coherent read
            out[base]     = sv[0] * inv;                     // phi1_mean (channel 0)
            out[base + 1] = sv[4] * inv;                     // phi5_mean (channel 4)
            #pragma unroll
            for (int i = 0; i < 10; ++i) out[base + 2 + i] = sv[i] * inv;  // field_means
        }
    }
}

extern "C" void kernel_launch(void* const* d_in, const int* in_sizes, int n_in,
                              void* d_out, int out_size, void* d_ws, size_t ws_size,
                              hipStream_t stream) {
    const float* phi     = (const float*)d_in[0];
    const float* sensory = (const float*)d_in[1];
    const float* gamma   = (const float*)d_in[2];
    const float* alpha   = (const float*)d_in[3];
    const float* mixw    = (const float*)d_in[4];
    float* out = (float*)d_out;
    float* sums = (float*)d_ws;

    hipMemsetAsync(sums, 0, 11 * sizeof(float), stream);   // 10 sums + done-counter

    step_kernel<<<dim3(NBLK), NT, 0, stream>>>(phi, sensory, gamma, alpha, mixw, out, sums);
}

// Round 5
// 267.847 us; speedup vs baseline: 1.0289x; 1.0289x over previous
//
#include <hip/hip_runtime.h>
#include <math.h>

#define HH 1536
#define WW 1536
#define HWSZ (HH*WW)
#define NT 384     // 384 threads x 2 px = 768 px = half row. 6 waves/block.
#define NBLK (HH*2)

// Session lessons (rounds 1-4):
//  - R1/R2: 256-thread blocks -> allocator targets 64 VGPR and spills 80-float
//    state to scratch (WRITE 92->312MB). amdgpu_waves_per_eu(4,4) didn't override.
//  - R3: __shfl x-halos SLOWER than redundant halo loads (dependent ds-chain
//    serializes; independent VMEM pipelines). Keep the loads.
//  - R4: fused finalize (__threadfence + done-counter per block) cost ~+50us:
//    device-scope fence = per-block L2 writeback+drain. Keep finalize separate.
//  - This round: ONLY change vs round-0 (114.6us) is 4px -> 2px per thread:
//    halves persistent state (80 -> 40 floats) so the 64-VGPR tier is reachable
//    WITHOUT spilling -> 2x resident waves in the latency-bound regime.

__device__ __forceinline__ float2 LD2(const float* __restrict__ p, int row, int idx) {
    return reinterpret_cast<const float2*>(p + row)[idx];
}

__global__ __launch_bounds__(NT) void step_kernel(
    const float* __restrict__ phi,
    const float* __restrict__ sensory,
    const float* __restrict__ gamma,
    const float* __restrict__ alpha,
    const float* __restrict__ mixw,
    float* __restrict__ out,
    float* __restrict__ sums)
{
    __shared__ float s_mix[100];
    __shared__ float s_g[10];
    __shared__ float s_a0;
    __shared__ float s_red[6][10];

    const int tid = threadIdx.x;
    if (tid < 100) s_mix[tid] = mixw[tid];
    if (tid < 10)  s_g[tid]   = gamma[tid];
    if (tid == 0)  s_a0       = alpha[0];
    __syncthreads();

    // XCD-banded swizzle: 3072 blocks round-robin over 8 XCDs; each XCD gets a
    // contiguous 384-block band = 192 rows, so stencil row-reuse hits its own L2.
    const int blk = blockIdx.x;
    const int nb   = (blk & 7) * 384 + (blk >> 3);   // banded block id
    const int y    = nb >> 1;                        // row
    const int half = nb & 1;                         // left/right half of row

    const int col = half * 384 + tid;   // float2 index within row
    const int x0  = col * 2;            // first pixel x of this thread

    const int ym1 = (y == 0)      ? HH - 1     : y - 1;
    const int yp1 = (y == HH - 1) ? 0          : y + 1;
    const int ym2 = (y < 2)       ? y + HH - 2 : y - 2;
    const int yp2 = (y >= HH - 2) ? y - HH + 2 : y + 2;

    const int r0  = y   * WW;
    const int rm1 = ym1 * WW;
    const int rp1 = yp1 * WW;
    const int rm2 = ym2 * WW;
    const int rp2 = yp2 * WW;

    // x halo indices (x0 is a multiple of 2; x0==0 is the only left-wrap case)
    const int xl1 = (x0 == 0)      ? WW - 1 : x0 - 1;
    const int xl2 = (x0 == 0)      ? WW - 2 : x0 - 2;
    const int xr1 = (x0 + 2 == WW) ? 0      : x0 + 2;
    const int xr2 = (x0 + 2 == WW) ? 1      : x0 + 3;

    float pv[10][2];   // phi values (kept for coupling)
    float dv[10][2];   // per-channel dphi (nonlinear + lap/bilap part)

    #pragma unroll
    for (int c = 0; c < 10; ++c) {
        const float* pc = phi + (size_t)c * HWSZ;
        const float2 cm = LD2(pc, r0,  col);
        const float2 nn = LD2(pc, rm1, col);
        const float2 ss = LD2(pc, rp1, col);
        const float wl1 = pc[r0 + xl1];
        const float wr1 = pc[r0 + xr1];

        float lap[2];
        lap[0] = nn.x + ss.x + wl1  + cm.y - 4.0f * cm.x;
        lap[1] = nn.y + ss.y + cm.x + wr1  - 4.0f * cm.y;

        float bl[2] = {0.f, 0.f};
        if (c == 0 || c == 3 || c == 4 || c == 9) {
            // direct 13-pt bilaplacian: 20c -8(N+S+W+E) +2(diag) + (NN+SS+WW+EE)
            const float2 t2n = LD2(pc, rm2, col);
            const float2 t2s = LD2(pc, rp2, col);
            const float wl2 = pc[r0  + xl2];
            const float wr2 = pc[r0  + xr2];
            const float nwl = pc[rm1 + xl1];
            const float ner = pc[rm1 + xr1];
            const float swl = pc[rp1 + xl1];
            const float ser = pc[rp1 + xr1];
            bl[0] = 20.0f*cm.x - 8.0f*(nn.x + ss.x + wl1  + cm.y)
                  + 2.0f*(nwl  + nn.y + swl + ss.y) + (t2n.x + t2s.x + wl2 + wr1);
            bl[1] = 20.0f*cm.y - 8.0f*(nn.y + ss.y + cm.x + wr1)
                  + 2.0f*(nn.x + ner  + ss.x + ser) + (t2n.y + t2s.y + wl1 + wr2);
        }

        pv[c][0] = cm.x; pv[c][1] = cm.y;

        #pragma unroll
        for (int k = 0; k < 2; ++k) {
            const float pp = pv[c][k];
            const float lv = lap[k];
            const float bv = bl[k];
            float dd;
            switch (c) {
            case 0: dd = -s_g[0]*lv - s_a0*pp*pp*pp + 0.12f*bv; break;
            case 1: dd = -s_g[1]*lv + 0.15f*sinf(pp) + 0.08f*pp*pp*pp; break;
            case 2: dd = -s_g[2]*lv + 0.2f*pp*(1.0f - pp*pp); break;
            case 3: { const float p2 = pp*pp;
                      dd = -s_g[3]*lv - 0.03f*p2*p2*pp + 0.08f*bv; } break;
            case 4: dd = -s_g[4]*lv + 0.12f*pp*logf(fabsf(pp) + 1e-6f) + 0.02f*bv; break;
            case 5: { const float p2 = pp*pp;
                      dd = -s_g[5]*lv + 0.08f*p2*pp - 0.02f*p2*p2*pp; } break;
            case 6: { const float p2 = pp*pp;
                      dd = -s_g[6]*lv + 0.06f*p2*p2 - 0.04f*pp; } break;
            case 7: { const float pc7 = fminf(fmaxf(pp, -2.0f), 2.0f);
                      dd = -s_g[7]*lv + 0.08f*sinhf(pc7); } break;
            case 8: dd = -s_g[8]*lv + 0.05f*pp*pp - 0.08f*pp; break;
            default: { const float p3 = pp*pp*pp;
                       dd = -s_g[9]*lv + 0.02f*p3*p3 - 0.04f*p3 + 0.01f*bv; } break;
            }
            dv[c][k] = dd;
        }
    }

    float fmv[2], smv[2], sdk[2];
    {
        const float2 sd2 = LD2(sensory, r0, col);
        sdk[0] = sd2.x; sdk[1] = sd2.y;
        #pragma unroll
        for (int k = 0; k < 2; ++k) {
            fmv[k] = (pv[0][k] + pv[1][k] + pv[2][k] + pv[3][k] + pv[4][k]) * 0.2f;
            smv[k] = (pv[5][k] + pv[6][k] + pv[7][k] + pv[8][k] + pv[9][k]) * 0.2f;
        }
    }

    const int lane = tid & 63;
    const int wave = tid >> 6;

    #pragma unroll
    for (int o = 0; o < 10; ++o) {
        float pn[2];
        #pragma unroll
        for (int k = 0; k < 2; ++k) {
            float cp = 0.0f;
            #pragma unroll
            for (int c = 0; c < 10; ++c) cp = fmaf(s_mix[o*10 + c], pv[c][k], cp);
            float dd = dv[o][k];
            if (o < 5) {
                dd += 0.06f * cp + 0.02f * smv[k];          // EPS_FAST, S2F
                if (o == 0) dd += 0.2f  * sdk[k];
                if (o == 4) dd += 0.08f * fabsf(sdk[k]);
                pn[k] = pv[o][k] + 0.02f * dd;              // DT * FAST_DT
            } else {
                dd += 0.02f * cp + 0.04f * fmv[k];          // EPS_SLOW, F2S
                if (o == 9) dd += 0.05f * sdk[k];
                pn[k] = pv[o][k] + 0.004f * dd;             // DT * SLOW_DT
            }
            pn[k] = fminf(fmaxf(pn[k], -4.0f), 4.0f);
        }
        float2 o2; o2.x = pn[0]; o2.y = pn[1];
        reinterpret_cast<float2*>(out + (size_t)o * HWSZ + r0)[col] = o2;

        float s = pn[0] + pn[1];
        #pragma unroll
        for (int off = 32; off > 0; off >>= 1) s += __shfl_down(s, off, 64);
        if (lane == 0) s_red[wave][o] = s;
    }

    __syncthreads();
    if (tid < 10) {
        float v = 0.0f;
        #pragma unroll
        for (int w = 0; w < 6; ++w) v += s_red[w][tid];
        atomicAdd(&sums[tid], v);
    }
}

__global__ void finalize_kernel(const float* __restrict__ sums,
                                float* __restrict__ out)
{
    const int t = threadIdx.x;
    const float inv = 1.0f / (float)HWSZ;
    const size_t base = (size_t)10 * HWSZ;
    if (t == 0) out[base]     = sums[0] * inv;  // phi1_mean (channel 0)
    if (t == 1) out[base + 1] = sums[4] * inv;  // phi5_mean (channel 4)
    if (t >= 2 && t < 12) out[base + 2 + (t - 2)] = sums[t - 2] * inv;  // field_means
}

extern "C" void kernel_launch(void* const* d_in, const int* in_sizes, int n_in,
                              void* d_out, int out_size, void* d_ws, size_t ws_size,
                              hipStream_t stream) {
    const float* phi     = (const float*)d_in[0];
    const float* sensory = (const float*)d_in[1];
    const float* gamma   = (const float*)d_in[2];
    const float* alpha   = (const float*)d_in[3];
    const float* mixw    = (const float*)d_in[4];
    float* out = (float*)d_out;
    float* sums = (float*)d_ws;

    hipMemsetAsync(sums, 0, 10 * sizeof(float), stream);

    step_kernel<<<dim3(NBLK), NT, 0, stream>>>(phi, sensory, gamma, alpha, mixw, out, sums);
    finalize_kernel<<<1, 64, 0, stream>>>(sums, out);
}

// Round 6
// 242.638 us; speedup vs baseline: 1.1358x; 1.1039x over previous
//
#include <hip/hip_runtime.h>
#include <math.h>

#define HH 1536
#define WW 1536
#define HWSZ (HH*WW)
#define NT 256        // 4 waves/block, 2 px/thread -> 512 px = 1/3 row
#define NBLK (HH*3)   // 4608 blocks
#define BAND (NBLK/8) // 576 blocks per XCD band

// Session lessons (rounds 1-5):
//  - Wave-capacity tiers at VGPR={64,128,256}: 72 VGPR buys NOTHING over 112
//    (both 4 waves/SIMD). Must be <=64 for the 8-waves/SIMD tier. (R5)
//  - 256-thread blocks make the allocator naturally target 64 VGPR; fatal if
//    state doesn't fit (R1: 23-float spill), exactly right if it does.
//  - __shfl x-halos and fused-finalize (__threadfence/block) both regressed
//    (R3/R4). Keep redundant halo loads + separate finalize dispatch.
//  - This round: two-pass restructure. Pass A: center loads -> coupling
//    accumulators cp[10][2] + means (26-float persistent state, vs 40 for
//    pv+dv). Pass B: per-channel stencil+nonlinear+integrate, no carried state.

__device__ __forceinline__ float2 LD2(const float* __restrict__ p, int row, int idx) {
    return reinterpret_cast<const float2*>(p + row)[idx];
}

__global__ __launch_bounds__(NT) void step_kernel(
    const float* __restrict__ phi,
    const float* __restrict__ sensory,
    const float* __restrict__ gamma,
    const float* __restrict__ alpha,
    const float* __restrict__ mixw,
    float* __restrict__ out,
    float* __restrict__ sums)
{
    __shared__ float s_mix[100];
    __shared__ float s_g[10];
    __shared__ float s_a0;
    __shared__ float s_red[4][10];

    const int tid = threadIdx.x;
    if (tid < 100) s_mix[tid] = mixw[tid];
    if (tid < 10)  s_g[tid]   = gamma[tid];
    if (tid == 0)  s_a0       = alpha[0];
    __syncthreads();

    // XCD-banded swizzle: 4608 blocks round-robin over 8 XCDs; each XCD gets a
    // contiguous 576-block band = 192 rows, so stencil row-reuse hits its own L2.
    const int blk  = blockIdx.x;
    const int nb   = (blk & 7) * BAND + (blk >> 3);
    const int y    = nb / 3;            // row
    const int part = nb - y * 3;        // third of the row

    const int col = part * NT + tid;    // float2 index within row
    const int x0  = col * 2;            // first pixel x of this thread

    const int ym1 = (y == 0)      ? HH - 1     : y - 1;
    const int yp1 = (y == HH - 1) ? 0          : y + 1;
    const int ym2 = (y < 2)       ? y + HH - 2 : y - 2;
    const int yp2 = (y >= HH - 2) ? y - HH + 2 : y + 2;

    const int r0  = y   * WW;   // block-uniform -> SGPRs
    const int rm1 = ym1 * WW;
    const int rp1 = yp1 * WW;
    const int rm2 = ym2 * WW;
    const int rp2 = yp2 * WW;

    // x halo indices (x0 multiple of 2; x0==0 is the only left-wrap case)
    const int xl1 = (x0 == 0)      ? WW - 1 : x0 - 1;
    const int xl2 = (x0 == 0)      ? WW - 2 : x0 - 2;
    const int xr1 = (x0 + 2 == WW) ? 0      : x0 + 2;
    const int xr2 = (x0 + 2 == WW) ? 1      : x0 + 3;

    // ---- Pass A: center values -> coupling accumulators + group means ----
    float cp[10][2];
    #pragma unroll
    for (int o = 0; o < 10; ++o) { cp[o][0] = 0.0f; cp[o][1] = 0.0f; }
    float fm0 = 0.f, fm1 = 0.f, sm0 = 0.f, sm1 = 0.f;

    #pragma unroll
    for (int c = 0; c < 10; ++c) {
        const float2 v = LD2(phi + (size_t)c * HWSZ, r0, col);
        #pragma unroll
        for (int o = 0; o < 10; ++o) {
            const float m = s_mix[o * 10 + c];   // wave-uniform -> LDS broadcast
            cp[o][0] = fmaf(m, v.x, cp[o][0]);
            cp[o][1] = fmaf(m, v.y, cp[o][1]);
        }
        if (c < 5) { fm0 += v.x; fm1 += v.y; }
        else       { sm0 += v.x; sm1 += v.y; }
    }
    fm0 *= 0.2f; fm1 *= 0.2f; sm0 *= 0.2f; sm1 *= 0.2f;

    float sd0, sd1;
    {
        const float2 sd2 = LD2(sensory, r0, col);
        sd0 = sd2.x; sd1 = sd2.y;
    }

    const int lane = tid & 63;
    const int wave = tid >> 6;

    // ---- Pass B: per-channel stencil + nonlinear + integrate + store ----
    #pragma unroll
    for (int c = 0; c < 10; ++c) {
        const float* pc = phi + (size_t)c * HWSZ;
        const float2 cm = LD2(pc, r0,  col);     // center reload: L1/L2 hit
        const float2 nn = LD2(pc, rm1, col);
        const float2 ss = LD2(pc, rp1, col);
        const float wl1 = pc[r0 + xl1];
        const float wr1 = pc[r0 + xr1];

        float lap[2];
        lap[0] = nn.x + ss.x + wl1  + cm.y - 4.0f * cm.x;
        lap[1] = nn.y + ss.y + cm.x + wr1  - 4.0f * cm.y;

        float bl[2] = {0.f, 0.f};
        if (c == 0 || c == 3 || c == 4 || c == 9) {
            // direct 13-pt bilaplacian: 20c -8(N+S+W+E) +2(diag) + (NN+SS+WW+EE)
            const float2 t2n = LD2(pc, rm2, col);
            const float2 t2s = LD2(pc, rp2, col);
            const float wl2 = pc[r0  + xl2];
            const float wr2 = pc[r0  + xr2];
            const float nwl = pc[rm1 + xl1];
            const float ner = pc[rm1 + xr1];
            const float swl = pc[rp1 + xl1];
            const float ser = pc[rp1 + xr1];
            bl[0] = 20.0f*cm.x - 8.0f*(nn.x + ss.x + wl1  + cm.y)
                  + 2.0f*(nwl  + nn.y + swl + ss.y) + (t2n.x + t2s.x + wl2 + wr1);
            bl[1] = 20.0f*cm.y - 8.0f*(nn.y + ss.y + cm.x + wr1)
                  + 2.0f*(nn.x + ner  + ss.x + ser) + (t2n.y + t2s.y + wl1 + wr2);
        }

        const float pvk[2] = {cm.x, cm.y};
        float pn[2];
        #pragma unroll
        for (int k = 0; k < 2; ++k) {
            const float pp = pvk[k];
            const float lv = lap[k];
            const float bv = bl[k];
            float dd;
            switch (c) {
            case 0: dd = -s_g[0]*lv - s_a0*pp*pp*pp + 0.12f*bv; break;
            case 1: dd = -s_g[1]*lv + 0.15f*sinf(pp) + 0.08f*pp*pp*pp; break;
            case 2: dd = -s_g[2]*lv + 0.2f*pp*(1.0f - pp*pp); break;
            case 3: { const float p2 = pp*pp;
                      dd = -s_g[3]*lv - 0.03f*p2*p2*pp + 0.08f*bv; } break;
            case 4: dd = -s_g[4]*lv + 0.12f*pp*logf(fabsf(pp) + 1e-6f) + 0.02f*bv; break;
            case 5: { const float p2 = pp*pp;
                      dd = -s_g[5]*lv + 0.08f*p2*pp - 0.02f*p2*p2*pp; } break;
            case 6: { const float p2 = pp*pp;
                      dd = -s_g[6]*lv + 0.06f*p2*p2 - 0.04f*pp; } break;
            case 7: { const float pc7 = fminf(fmaxf(pp, -2.0f), 2.0f);
                      dd = -s_g[7]*lv + 0.08f*sinhf(pc7); } break;
            case 8: dd = -s_g[8]*lv + 0.05f*pp*pp - 0.08f*pp; break;
            default: { const float p3 = pp*pp*pp;
                       dd = -s_g[9]*lv + 0.02f*p3*p3 - 0.04f*p3 + 0.01f*bv; } break;
            }

            const float sdk = (k == 0) ? sd0 : sd1;
            if (c < 5) {
                dd += 0.06f * cp[c][k] + 0.02f * ((k == 0) ? sm0 : sm1);  // EPS_FAST, S2F
                if (c == 0) dd += 0.2f  * sdk;
                if (c == 4) dd += 0.08f * fabsf(sdk);
                pn[k] = pp + 0.02f * dd;                                  // DT * FAST_DT
            } else {
                dd += 0.02f * cp[c][k] + 0.04f * ((k == 0) ? fm0 : fm1);  // EPS_SLOW, F2S
                if (c == 9) dd += 0.05f * sdk;
                pn[k] = pp + 0.004f * dd;                                 // DT * SLOW_DT
            }
            pn[k] = fminf(fmaxf(pn[k], -4.0f), 4.0f);
        }

        float2 o2; o2.x = pn[0]; o2.y = pn[1];
        reinterpret_cast<float2*>(out + (size_t)c * HWSZ + r0)[col] = o2;

        float s = pn[0] + pn[1];
        #pragma unroll
        for (int off = 32; off > 0; off >>= 1) s += __shfl_down(s, off, 64);
        if (lane == 0) s_red[wave][c] = s;
    }

    __syncthreads();
    if (tid < 10) {
        float v = 0.0f;
        #pragma unroll
        for (int w = 0; w < 4; ++w) v += s_red[w][tid];
        atomicAdd(&sums[tid], v);
    }
}

__global__ void finalize_kernel(const float* __restrict__ sums,
                                float* __restrict__ out)
{
    const int t = threadIdx.x;
    const float inv = 1.0f / (float)HWSZ;
    const size_t base = (size_t)10 * HWSZ;
    if (t == 0) out[base]     = sums[0] * inv;  // phi1_mean (channel 0)
    if (t == 1) out[base + 1] = sums[4] * inv;  // phi5_mean (channel 4)
    if (t >= 2 && t < 12) out[base + 2 + (t - 2)] = sums[t - 2] * inv;  // field_means
}

extern "C" void kernel_launch(void* const* d_in, const int* in_sizes, int n_in,
                              void* d_out, int out_size, void* d_ws, size_t ws_size,
                              hipStream_t stream) {
    const float* phi     = (const float*)d_in[0];
    const float* sensory = (const float*)d_in[1];
    const float* gamma   = (const float*)d_in[2];
    const float* alpha   = (const float*)d_in[3];
    const float* mixw    = (const float*)d_in[4];
    float* out = (float*)d_out;
    float* sums = (float*)d_ws;

    hipMemsetAsync(sums, 0, 10 * sizeof(float), stream);

    step_kernel<<<dim3(NBLK), NT, 0, stream>>>(phi, sensory, gamma, alpha, mixw, out, sums);
    finalize_kernel<<<1, 64, 0, stream>>>(sums, out);
}